// Round 5
// baseline (660.452 us; speedup 1.0000x reference)
//
#include <hip/hip_runtime.h>

// ---------- types ----------
typedef short s16x8 __attribute__((ext_vector_type(8)));   // 8 bf16 (4 VGPRs)
typedef float f32x4 __attribute__((ext_vector_type(4)));

static __device__ __forceinline__ unsigned short f2bf(float f) {
  unsigned u = __builtin_bit_cast(unsigned, f);
  unsigned r = (u + 0x7FFFu + ((u >> 16) & 1u)) >> 16;   // RNE; inputs finite
  return (unsigned short)r;
}

#define KD 512
// B = 16, T = 512, C = 19, E = 512, H = 8, HD = 64
// groups = B*T = 8192; fused kernel: 2 groups (38 rows, padded to 48) per block.

// ---------- kernel: convert weights fp32 -> bf16, rows 0..511 = w_q, 512..1023 = w_k ----------
__global__ void k_convw(const float* __restrict__ wq, const float* __restrict__ wk,
                        unsigned short* __restrict__ Wb) {
  int idx = blockIdx.x * 256 + threadIdx.x;
  int f  = idx >> 6;
  int c8 = (idx & 63) << 3;
  const float* src = (f < 512) ? (wq + f * 512 + c8) : (wk + (f - 512) * 512 + c8);
  float4 v0 = *(const float4*)(src);
  float4 v1 = *(const float4*)(src + 4);
  s16x8 o;
  o[0] = (short)f2bf(v0.x); o[1] = (short)f2bf(v0.y); o[2] = (short)f2bf(v0.z); o[3] = (short)f2bf(v0.w);
  o[4] = (short)f2bf(v1.x); o[5] = (short)f2bf(v1.y); o[6] = (short)f2bf(v1.z); o[7] = (short)f2bf(v1.w);
  *(s16x8*)(Wb + f * 512 + c8) = o;
}

// ---------- fused kernel ----------
// Per block: 2 groups = 38 eeg rows (padded to 48 = 3 M-tiles).
//  A (48x512 bf16) in LDS, MFMA-fragment layout: frag f = kblk*3 + mblk (kblk = k>>5,
//    mblk = row>>4), lane lp = (row&15) + 16*((k>>3)&3), 16B/lane -> lane*16-linear reads.
//  Per head-pair step (4 steps): 4 waves project Q/K (wave = (qk, head-of-pair),
//    4 col-tiles each: 3 A-reads feed 12 MFMAs per k-step); Q/K written to LDS in
//    score-fragment layout; then score MFMAs (16x16, K=64) + in-register shfl softmax.
// Output: per-group sum of triu softmax masses -> LDS gsum -> global atomic.
__global__ __launch_bounds__(256, 2)
void k_fused(const float* __restrict__ A, const unsigned short* __restrict__ Wb,
             const float* __restrict__ bq, const float* __restrict__ bk,
             float* __restrict__ oacc, int nGroups) {
  __shared__ unsigned short Ap[48 * 512];   // 49,152 B (48 frags x 1 KB)
  __shared__ unsigned short Qb[12 * 512];   // 12,288 B (12 frags: 4 hd-chunks x 3 row-tiles)
  __shared__ unsigned short Kb[12 * 512];   // 12,288 B
  __shared__ float gsum[2];

  const int tid  = threadIdx.x;
  const int lane = tid & 63;
  const int wid  = tid >> 6;        // 0..3
  const int rlo  = lane & 15;
  const int rhi  = lane >> 4;

  const int g0 = blockIdx.x * 2;
  int ng = nGroups - g0; if (ng > 2) ng = 2;
  const int nvalid = ng * 19;       // 38 (or 19 edge)
  const long arow0 = (long)g0 * 19;

  char* ldsA = (char*)Ap;

  if (tid < 2) gsum[tid] = 0.f;

  // ---- stage A: each (iter, wave) fills exactly one 1KB frag (conflict-free) ----
#pragma unroll
  for (int r = 0; r < 12; ++r) {
    int combo = r * 4 + wid;                 // 0..47
    int kblk  = (combo * 171) >> 9;          // combo / 3
    int rblk  = combo - 3 * kblk;            // combo % 3
    int row   = rblk * 16 + (lane >> 2);
    int kc    = kblk * 4 + (lane & 3);       // 16B k-chunk index (8 bf16)
    s16x8 o = (s16x8){0, 0, 0, 0, 0, 0, 0, 0};
    if (row < nvalid) {
      const float* ap = A + (arow0 + row) * KD + kc * 8;
      float4 v0 = *(const float4*)(ap);
      float4 v1 = *(const float4*)(ap + 4);
      o[0]=(short)f2bf(v0.x); o[1]=(short)f2bf(v0.y); o[2]=(short)f2bf(v0.z); o[3]=(short)f2bf(v0.w);
      o[4]=(short)f2bf(v1.x); o[5]=(short)f2bf(v1.y); o[6]=(short)f2bf(v1.z); o[7]=(short)f2bf(v1.w);
    }
    *(s16x8*)(ldsA + (kblk * 3 + rblk) * 1024 + ((lane >> 2) + ((lane & 3) << 4)) * 16) = o;
  }
  __syncthreads();

  // ---- wave roles ----
  const int qk   = wid >> 1;        // 0 = Q, 1 = K
  const int hsel = wid & 1;         // head within pair
  char* dst = qk ? (char*)Kb : (char*)Qb;
  const float* bptr = qk ? bk : bq;

  // pacc: slot0 = task wid, slot1 = task wid+4 (waves 0,1 only)
  float pa00 = 0.f, pa01 = 0.f, pa02 = 0.f, pa03 = 0.f;
  float pa10 = 0.f, pa11 = 0.f, pa12 = 0.f, pa13 = 0.f;

#define MFMA_BF16 __builtin_amdgcn_mfma_f32_16x16x32_bf16

#define ROWP(J, PA) do { \
    int row_ = srt_ * 16 + (rhi << 2) + (J); \
    int g_   = (row_ * 27) >> 9; \
    int lo_  = g_ * 19; \
    float v0_ = s0[J] * 0.125f, v1_ = s1[J] * 0.125f, v2_ = s2[J] * 0.125f; \
    int c0_ = rlo, c1_ = rlo + 16, c2_ = rlo + 32; \
    bool i0_ = (c0_ >= lo_) && (c0_ < lo_ + 19); \
    bool i1_ = (c1_ >= lo_) && (c1_ < lo_ + 19); \
    bool i2_ = (c2_ >= lo_) && (c2_ < lo_ + 19); \
    float m_ = fmaxf(fmaxf(i0_ ? v0_ : -3e38f, i1_ ? v1_ : -3e38f), i2_ ? v2_ : -3e38f); \
    m_ = fmaxf(m_, __shfl_xor(m_, 1)); m_ = fmaxf(m_, __shfl_xor(m_, 2)); \
    m_ = fmaxf(m_, __shfl_xor(m_, 4)); m_ = fmaxf(m_, __shfl_xor(m_, 8)); \
    float e0_ = i0_ ? __expf(v0_ - m_) : 0.f; \
    float e1_ = i1_ ? __expf(v1_ - m_) : 0.f; \
    float e2_ = i2_ ? __expf(v2_ - m_) : 0.f; \
    float se_ = e0_ + e1_ + e2_; \
    float up_ = ((c0_ > row_) ? e0_ : 0.f) + ((c1_ > row_) ? e1_ : 0.f) + ((c2_ > row_) ? e2_ : 0.f); \
    se_ += __shfl_xor(se_, 1); se_ += __shfl_xor(se_, 2); se_ += __shfl_xor(se_, 4); se_ += __shfl_xor(se_, 8); \
    up_ += __shfl_xor(up_, 1); up_ += __shfl_xor(up_, 2); up_ += __shfl_xor(up_, 4); up_ += __shfl_xor(up_, 8); \
    PA += (row_ < nvalid) ? (up_ / se_) : 0.f; \
  } while (0)

#define SCORES(TT, PA0, PA1, PA2, PA3) do { \
    const int t_   = (TT); \
    const int shs_ = (t_ >= 3) ? 1 : 0; \
    const int srt_ = t_ - 3 * shs_; \
    f32x4 s0 = (f32x4){0.f,0.f,0.f,0.f}, s1 = (f32x4){0.f,0.f,0.f,0.f}, s2 = (f32x4){0.f,0.f,0.f,0.f}; \
    { \
      const char* qb_ = (const char*)Qb + ((shs_ * 2) * 3 + srt_) * 1024 + lane * 16; \
      const char* kb_ = (const char*)Kb + ((shs_ * 2) * 3) * 1024 + lane * 16; \
      s16x8 qa0 = *(const s16x8*)(qb_); \
      s16x8 k0  = *(const s16x8*)(kb_); \
      s16x8 k1  = *(const s16x8*)(kb_ + 1024); \
      s16x8 k2  = *(const s16x8*)(kb_ + 2048); \
      s0 = MFMA_BF16(qa0, k0, s0, 0, 0, 0); \
      s1 = MFMA_BF16(qa0, k1, s1, 0, 0, 0); \
      s2 = MFMA_BF16(qa0, k2, s2, 0, 0, 0); \
      s16x8 qa1 = *(const s16x8*)(qb_ + 3 * 1024); \
      s16x8 k3  = *(const s16x8*)(kb_ + 3 * 1024); \
      s16x8 k4  = *(const s16x8*)(kb_ + 4 * 1024); \
      s16x8 k5  = *(const s16x8*)(kb_ + 5 * 1024); \
      s0 = MFMA_BF16(qa1, k3, s0, 0, 0, 0); \
      s1 = MFMA_BF16(qa1, k4, s1, 0, 0, 0); \
      s2 = MFMA_BF16(qa1, k5, s2, 0, 0, 0); \
    } \
    ROWP(0, PA0); ROWP(1, PA1); ROWP(2, PA2); ROWP(3, PA3); \
  } while (0)

#define WOUT(M, N, CREG, BIASV) do { \
    int fq_ = ((hsel << 1) + ((N) >> 1)) * 3 + (M); \
    int lf_ = (rhi << 2) + ((((N) & 1) << 1) + (rlo >> 3)) * 16; \
    char* p_ = dst + fq_ * 1024 + lf_ * 16 + ((rlo & 7) << 1); \
    *(unsigned short*)(p_)      = f2bf(CREG[0] + BIASV); \
    *(unsigned short*)(p_ + 16) = f2bf(CREG[1] + BIASV); \
    *(unsigned short*)(p_ + 32) = f2bf(CREG[2] + BIASV); \
    *(unsigned short*)(p_ + 48) = f2bf(CREG[3] + BIASV); \
  } while (0)

#pragma unroll 1
  for (int hh = 0; hh < 8; hh += 2) {
    const int h = hh + hsel;

    // ---- projection: 48 rows x 64 cols (this wave's qk/head), K = 512 ----
    f32x4 c00 = (f32x4){0.f,0.f,0.f,0.f}, c01 = c00, c02 = c00, c03 = c00;
    f32x4 c10 = c00, c11 = c00, c12 = c00, c13 = c00;
    f32x4 c20 = c00, c21 = c00, c22 = c00, c23 = c00;

    const unsigned short* bp0 = Wb + ((long)(qk * 512 + h * 64 + rlo)) * KD + rhi * 8;
    const unsigned short* bp1 = bp0 + 16 * KD;
    const unsigned short* bp2 = bp0 + 32 * KD;
    const unsigned short* bp3 = bp0 + 48 * KD;

#pragma unroll
    for (int ks = 0; ks < 16; ++ks) {
      s16x8 b0 = *(const s16x8*)(bp0 + ks * 32);
      s16x8 b1 = *(const s16x8*)(bp1 + ks * 32);
      s16x8 b2 = *(const s16x8*)(bp2 + ks * 32);
      s16x8 b3 = *(const s16x8*)(bp3 + ks * 32);
      s16x8 a0 = *(const s16x8*)(ldsA + ((ks * 3 + 0) << 10) + lane * 16);
      s16x8 a1 = *(const s16x8*)(ldsA + ((ks * 3 + 1) << 10) + lane * 16);
      s16x8 a2 = *(const s16x8*)(ldsA + ((ks * 3 + 2) << 10) + lane * 16);
      c00 = MFMA_BF16(a0, b0, c00, 0, 0, 0);
      c01 = MFMA_BF16(a0, b1, c01, 0, 0, 0);
      c02 = MFMA_BF16(a0, b2, c02, 0, 0, 0);
      c03 = MFMA_BF16(a0, b3, c03, 0, 0, 0);
      c10 = MFMA_BF16(a1, b0, c10, 0, 0, 0);
      c11 = MFMA_BF16(a1, b1, c11, 0, 0, 0);
      c12 = MFMA_BF16(a1, b2, c12, 0, 0, 0);
      c13 = MFMA_BF16(a1, b3, c13, 0, 0, 0);
      c20 = MFMA_BF16(a2, b0, c20, 0, 0, 0);
      c21 = MFMA_BF16(a2, b1, c21, 0, 0, 0);
      c22 = MFMA_BF16(a2, b2, c22, 0, 0, 0);
      c23 = MFMA_BF16(a2, b3, c23, 0, 0, 0);
    }

    // ---- write Q/K into score-fragment LDS (with bias) ----
    {
      float bias0 = bptr[h * 64 + rlo];
      float bias1 = bptr[h * 64 + 16 + rlo];
      float bias2 = bptr[h * 64 + 32 + rlo];
      float bias3 = bptr[h * 64 + 48 + rlo];
      WOUT(0, 0, c00, bias0); WOUT(0, 1, c01, bias1); WOUT(0, 2, c02, bias2); WOUT(0, 3, c03, bias3);
      WOUT(1, 0, c10, bias0); WOUT(1, 1, c11, bias1); WOUT(1, 2, c12, bias2); WOUT(1, 3, c13, bias3);
      WOUT(2, 0, c20, bias0); WOUT(2, 1, c21, bias1); WOUT(2, 2, c22, bias2); WOUT(2, 3, c23, bias3);
    }
    __syncthreads();

    // ---- scores + softmax (tasks: (head-of-pair, row-tile), 6 tasks on 4 waves) ----
    SCORES(wid, pa00, pa01, pa02, pa03);
    if (wid < 2) { SCORES(wid + 4, pa10, pa11, pa12, pa13); }
    __syncthreads();
  }

  // ---- accumulate per-group sums ----
  {
    const int t_ = wid; const int shs_ = (t_ >= 3) ? 1 : 0; const int srt_ = t_ - 3 * shs_;
    if (rlo == 0) {
      int r0 = srt_ * 16 + (rhi << 2);
      if (r0 + 0 < nvalid) atomicAdd(&gsum[((r0 + 0) * 27) >> 9], pa00);
      if (r0 + 1 < nvalid) atomicAdd(&gsum[((r0 + 1) * 27) >> 9], pa01);
      if (r0 + 2 < nvalid) atomicAdd(&gsum[((r0 + 2) * 27) >> 9], pa02);
      if (r0 + 3 < nvalid) atomicAdd(&gsum[((r0 + 3) * 27) >> 9], pa03);
    }
  }
  if (wid < 2) {
    const int t_ = wid + 4; const int srt_ = t_ - 3;
    if (rlo == 0) {
      int r0 = srt_ * 16 + (rhi << 2);
      if (r0 + 0 < nvalid) atomicAdd(&gsum[((r0 + 0) * 27) >> 9], pa10);
      if (r0 + 1 < nvalid) atomicAdd(&gsum[((r0 + 1) * 27) >> 9], pa11);
      if (r0 + 2 < nvalid) atomicAdd(&gsum[((r0 + 2) * 27) >> 9], pa12);
      if (r0 + 3 < nvalid) atomicAdd(&gsum[((r0 + 3) * 27) >> 9], pa13);
    }
  }
  __syncthreads();
  if (tid < ng) atomicAdd(&oacc[(g0 + tid) >> 9], gsum[tid]);

#undef ROWP
#undef SCORES
#undef WOUT
#undef MFMA_BF16
}

// ---------- kernel: finalize out[b] = clip(acc[b] / (8*171*512), 0, 1) ----------
__global__ void k_fin(const float* __restrict__ acc, float* __restrict__ out) {
  int t = threadIdx.x;
  if (t < 16) {
    float v = acc[t] * (1.0f / 700416.0f);
    out[t] = fminf(1.0f, fmaxf(0.0f, v));
  }
}

// ---------- host ----------
extern "C" void kernel_launch(void* const* d_in, const int* in_sizes, int n_in,
                              void* d_out, int out_size, void* d_ws, size_t ws_size,
                              hipStream_t stream) {
  const float* eeg = (const float*)d_in[0];
  const float* wq  = (const float*)d_in[1];
  const float* wk  = (const float*)d_in[2];
  const float* bq  = (const float*)d_in[3];
  const float* bk  = (const float*)d_in[4];
  float* out = (float*)d_out;

  char* ws = (char*)d_ws;
  unsigned short* Wb = (unsigned short*)ws;      // 1 MiB bf16 weights [1024][512]
  float* acc = (float*)(ws + (1 << 20));         // 64 B accumulators

  hipMemsetAsync(acc, 0, 64, stream);
  k_convw<<<256, 256, 0, stream>>>(wq, wk, Wb);
  k_fused<<<4096, 256, 0, stream>>>(eeg, Wb, bq, bk, acc, 8192);
  k_fin<<<1, 64, 0, stream>>>(acc, out);
}

// Round 6
// 461.094 us; speedup vs baseline: 1.4324x; 1.4324x over previous
//
#include <hip/hip_runtime.h>

// ---------- types ----------
typedef short s16x8 __attribute__((ext_vector_type(8)));   // 8 bf16 (4 VGPRs)
typedef float f32x4 __attribute__((ext_vector_type(4)));

static __device__ __forceinline__ unsigned short f2bf(float f) {
  unsigned u = __builtin_bit_cast(unsigned, f);
  return (unsigned short)((u + 0x7FFFu + ((u >> 16) & 1u)) >> 16);   // RNE; finite
}

// async global->LDS, 16B per lane; LDS dst must be wave-uniform base (lane*16 implicit)
#define GLL16(G, L) __builtin_amdgcn_global_load_lds( \
    (const __attribute__((address_space(1))) void*)(G), \
    (__attribute__((address_space(3))) void*)(L), 16, 0, 0)

#define KD 512
// B=16, T=512, C=19, E=512, H=8, HD=64; groups = 8192, rows = 155648.
// Fragment layout everywhere: frag (tile16, ktile32) = 1 KB: lane lf = (row&15) + 16*jc
// holds 16 B (8 bf16) at [row][ktile*32 + jc*8]. MFMA A/B reads are lane*16-linear.

// ---------- kernel: eeg fp32 -> bf16 fragment layout ----------
// thread = (mtile, slot): writes 1 KB frags coalesced; reads 32 B per lane (full lines).
__global__ __launch_bounds__(256)
void k_conva(const float* __restrict__ src, unsigned short* __restrict__ dst) {
  int gid = blockIdx.x * 256 + threadIdx.x;
  int mt = gid >> 10, slot = gid & 1023;
  int kt = slot >> 6, lf = slot & 63;
  int row = mt * 16 + (lf & 15);
  int jc  = lf >> 4;
  const float* p = src + (long)row * KD + kt * 32 + jc * 8;
  float4 v0 = *(const float4*)p;
  float4 v1 = *(const float4*)(p + 4);
  s16x8 o;
  o[0]=(short)f2bf(v0.x); o[1]=(short)f2bf(v0.y); o[2]=(short)f2bf(v0.z); o[3]=(short)f2bf(v0.w);
  o[4]=(short)f2bf(v1.x); o[5]=(short)f2bf(v1.y); o[6]=(short)f2bf(v1.z); o[7]=(short)f2bf(v1.w);
  *(s16x8*)(dst + ((long)mt * 16 + kt) * 512 + (long)lf * 8) = o;
}

// ---------- kernel: weights fp32 -> bf16 fragment layout (rows 0..511 wq, 512..1023 wk) ----------
__global__ __launch_bounds__(256)
void k_convw(const float* __restrict__ wq, const float* __restrict__ wk,
             unsigned short* __restrict__ Wf) {
  int gid = blockIdx.x * 256 + threadIdx.x;   // 65536 threads
  int nt = gid >> 10, slot = gid & 1023;
  int kt = slot >> 6, lf = slot & 63;
  int f  = nt * 16 + (lf & 15);
  int jc = lf >> 4;
  const float* p = ((f < 512) ? (wq + (long)f * KD) : (wk + (long)(f - 512) * KD)) + kt * 32 + jc * 8;
  float4 v0 = *(const float4*)p;
  float4 v1 = *(const float4*)(p + 4);
  s16x8 o;
  o[0]=(short)f2bf(v0.x); o[1]=(short)f2bf(v0.y); o[2]=(short)f2bf(v0.z); o[3]=(short)f2bf(v0.w);
  o[4]=(short)f2bf(v1.x); o[5]=(short)f2bf(v1.y); o[6]=(short)f2bf(v1.z); o[7]=(short)f2bf(v1.w);
  *(s16x8*)(Wf + ((long)nt * 16 + kt) * 512 + (long)lf * 8) = o;
}

// ---------- kernel: QK = A @ [Wq^T | Wk^T] + bias (m97 structure) ----------
// 128x128 tile, BK=64, 256 thr (4 waves 2x2), single 32 KB buffer, 2-barrier K-loop,
// all staging via global_load_lds w=16 from fragment-ordered Af/Wf. LDS reads lane*16-linear.
__global__ __launch_bounds__(256, 4)
void k_gemm(const unsigned short* __restrict__ Af, const unsigned short* __restrict__ Wf,
            const float* __restrict__ bq, const float* __restrict__ bk,
            unsigned short* __restrict__ QK) {
  __shared__ unsigned short Abuf[16 * 512];   // 16 frags: slot = ksub*8 + msub
  __shared__ unsigned short Bbuf[16 * 512];   // 16 frags: slot = ksub*8 + nsub

  const int tid  = threadIdx.x;
  const int lane = tid & 63;
  const int wid  = tid >> 6;      // 0..3
  const int wr   = wid >> 1, wc = wid & 1;
  const int rlo  = lane & 15, rhi = lane >> 4;
  const int mb   = blockIdx.x >> 3;
  const int bn   = blockIdx.x & 7;   // bn-inner: 8 consecutive blocks share the A panel

#define STAGE(KK) do { \
    if (wid < 2) { \
      _Pragma("unroll") for (int s = 0; s < 8; ++s) { \
        int slot = wid * 8 + s; \
        const unsigned short* g = Af + ((long)(mb * 8 + (slot & 7)) * 16 + (KK) * 2 + (slot >> 3)) * 512 + lane * 8; \
        GLL16(g, &Abuf[slot * 512]); \
      } \
    } else { \
      _Pragma("unroll") for (int s = 0; s < 8; ++s) { \
        int slot = (wid - 2) * 8 + s; \
        const unsigned short* g = Wf + ((long)(bn * 8 + (slot & 7)) * 16 + (KK) * 2 + (slot >> 3)) * 512 + lane * 8; \
        GLL16(g, &Bbuf[slot * 512]); \
      } \
    } \
  } while (0)

  f32x4 acc[4][4] = {};
  STAGE(0);
  __syncthreads();   // drains vmcnt(0): buffer ready

#pragma unroll 1
  for (int kk = 0; kk < 8; ++kk) {
#pragma unroll
    for (int ksub = 0; ksub < 2; ++ksub) {
      s16x8 af[4], bfr[4];
#pragma unroll
      for (int m = 0; m < 4; ++m)
        af[m] = *(const s16x8*)&Abuf[(ksub * 8 + wr * 4 + m) * 512 + lane * 8];
#pragma unroll
      for (int n = 0; n < 4; ++n)
        bfr[n] = *(const s16x8*)&Bbuf[(ksub * 8 + wc * 4 + n) * 512 + lane * 8];
#pragma unroll
      for (int m = 0; m < 4; ++m)
#pragma unroll
        for (int n = 0; n < 4; ++n)
          acc[m][n] = __builtin_amdgcn_mfma_f32_16x16x32_bf16(af[m], bfr[n], acc[m][n], 0, 0, 0);
    }
    if (kk < 7) {
      __syncthreads();     // all reads of buffer done
      STAGE(kk + 1);
      __syncthreads();     // vmcnt(0) drain: next buffer ready
    }
  }
#undef STAGE

  // ---- epilogue: bias + bf16 store ----
#pragma unroll
  for (int n = 0; n < 4; ++n) {
    int colg = bn * 128 + wc * 64 + n * 16 + rlo;
    float bias = (colg < 512) ? bq[colg] : bk[colg - 512];
#pragma unroll
    for (int m = 0; m < 4; ++m) {
      long rl = (long)mb * 128 + wr * 64 + m * 16 + (rhi << 2);
#pragma unroll
      for (int j = 0; j < 4; ++j)
        QK[(rl + j) * 1024 + colg] = f2bf(acc[m][n][j] + bias);
    }
  }
}

// ---------- kernel: per-group attention -> atomic strength accumulation ----------
__global__ __launch_bounds__(256, 3)
void k_attn(const unsigned short* __restrict__ QK, float* __restrict__ acc, int g0) {
  __shared__ unsigned short Qs[19][1032];
  __shared__ float Sc[8][19][20];
  __shared__ float red[256];

  const int tid  = threadIdx.x;
  const int lane = tid & 63;
  const int wid  = tid >> 6;
  const long gl  = blockIdx.x;

  const unsigned short* src = QK + gl * 19 * 1024;
  for (int c = tid; c < 2432; c += 256) {
    int row = c >> 7, c8 = (c & 127) << 3;
    *(s16x8*)&Qs[row][c8] = *(const s16x8*)(src + row * 1024 + c8);
  }
  __syncthreads();

  const int rlo = lane & 15, rhi = lane >> 4;
  const s16x8 z8 = {};
#pragma unroll
  for (int hh = 0; hh < 2; ++hh) {
    const int h = wid * 2 + hh;
    f32x4 s[2][2] = {};
#pragma unroll
    for (int ks = 0; ks < 2; ++ks) {
      s16x8 qa[2], kb[2];
#pragma unroll
      for (int mi = 0; mi < 2; ++mi) {
        int r = mi * 16 + rlo;
        qa[mi] = (r < 19) ? *(const s16x8*)&Qs[r][h * 64 + ks * 32 + rhi * 8] : z8;
        kb[mi] = (r < 19) ? *(const s16x8*)&Qs[r][512 + h * 64 + ks * 32 + rhi * 8] : z8;
      }
#pragma unroll
      for (int mi = 0; mi < 2; ++mi)
#pragma unroll
        for (int nj = 0; nj < 2; ++nj)
          s[mi][nj] = __builtin_amdgcn_mfma_f32_16x16x32_bf16(qa[mi], kb[nj], s[mi][nj], 0, 0, 0);
    }
#pragma unroll
    for (int mi = 0; mi < 2; ++mi)
#pragma unroll
      for (int nj = 0; nj < 2; ++nj)
#pragma unroll
        for (int j = 0; j < 4; ++j) {
          int r = mi * 16 + rhi * 4 + j, c = nj * 16 + rlo;
          if (r < 19 && c < 19) Sc[h][r][c] = s[mi][nj][j] * 0.125f;
        }
  }
  __syncthreads();

  float p = 0.f;
  if (tid < 152) {
    int h = tid / 19, i = tid - h * 19;
    float sv[19];
    float mx = -1e30f;
#pragma unroll
    for (int j = 0; j < 19; ++j) { sv[j] = Sc[h][i][j]; mx = fmaxf(mx, sv[j]); }
    float sum = 0.f, up = 0.f;
#pragma unroll
    for (int j = 0; j < 19; ++j) {
      float e = __expf(sv[j] - mx);
      sum += e;
      if (j > i) up += e;
    }
    p = up / sum;
  }
  red[tid] = p;
  __syncthreads();
  for (int off = 128; off > 0; off >>= 1) {
    if (tid < off) red[tid] += red[tid + off];
    __syncthreads();
  }
  if (tid == 0) {
    int b = (g0 + (int)blockIdx.x) >> 9;
    atomicAdd(&acc[b], red[0]);
  }
}

// ---------- kernel: finalize out[b] = clip(acc[b] / (8*171*512), 0, 1) ----------
__global__ void k_fin(const float* __restrict__ acc, float* __restrict__ out) {
  int t = threadIdx.x;
  if (t < 16) {
    float v = acc[t] * (1.0f / 700416.0f);
    out[t] = fminf(1.0f, fmaxf(0.0f, v));
  }
}

// ---------- host ----------
extern "C" void kernel_launch(void* const* d_in, const int* in_sizes, int n_in,
                              void* d_out, int out_size, void* d_ws, size_t ws_size,
                              hipStream_t stream) {
  const float* eeg = (const float*)d_in[0];
  const float* wq  = (const float*)d_in[1];
  const float* wk  = (const float*)d_in[2];
  const float* bq  = (const float*)d_in[3];
  const float* bk  = (const float*)d_in[4];
  float* out = (float*)d_out;

  char* ws = (char*)d_ws;
  unsigned short* Wf = (unsigned short*)ws;          // 1 MiB frag-layout weights
  float* acc = (float*)(ws + (1 << 20));             // 64 B accumulators
  long off = (1 << 20) + 256;

  // per-group: Af 19*512*2 = 19456 B, QK 19*1024*2 = 38912 B
  long avail = (long)ws_size - off;
  long G = avail / 58368;
  G = (G / 128) * 128;
  if (G > 8192) G = 8192;
  if (G < 128) G = 128;
  unsigned short* Afb = (unsigned short*)(ws + off);
  unsigned short* QKb = (unsigned short*)(ws + off + G * 19456L);

  hipMemsetAsync(acc, 0, 64, stream);
  k_convw<<<256, 256, 0, stream>>>(wq, wk, Wf);

  for (int g0 = 0; g0 < 8192; g0 += (int)G) {
    int cg = 8192 - g0; if (cg > (int)G) cg = (int)G;
    int rows   = cg * 19;            // multiple of 2432 (cg multiple of 128)
    int mtiles = rows / 16;
    k_conva<<<mtiles * 4, 256, 0, stream>>>(eeg + (long)g0 * 19 * KD, Afb);
    k_gemm<<<(rows / 128) * 8, 256, 0, stream>>>(Afb, Wf, bq, bk, QKb);
    k_attn<<<cg, 256, 0, stream>>>(QKb, acc, g0);
  }
  k_fin<<<1, 64, 0, stream>>>(acc, out);
}